// Round 2
// baseline (327.519 us; speedup 1.0000x reference)
//
#include <hip/hip_runtime.h>
#include <float.h>

#define BB 256
#define DD 256
#define KK 1024
#define EE 16
#define DECAY 0.999f
#define GAIN  0.001f
#define EPS   1e-6f

// output offsets in floats (tuple order: cw_embed, one_hot, new_codebook, new_ema)
#define OH_OFF   ((size_t)BB * DD * EE)                    // 1048576
#define CB_OFF   (OH_OFF + (size_t)BB * DD * KK)           // 68157440
#define EMA_OFF  (CB_OFF + (size_t)DD * KK * EE)           // 72351744

__device__ __forceinline__ float dot16(const float4& a0, const float4& a1,
                                       const float4& a2, const float4& a3,
                                       const float4& b0, const float4& b1,
                                       const float4& b2, const float4& b3) {
  float s = a0.x * b0.x;
  s = fmaf(a0.y, b0.y, s); s = fmaf(a0.z, b0.z, s); s = fmaf(a0.w, b0.w, s);
  s = fmaf(a1.x, b1.x, s); s = fmaf(a1.y, b1.y, s); s = fmaf(a1.z, b1.z, s); s = fmaf(a1.w, b1.w, s);
  s = fmaf(a2.x, b2.x, s); s = fmaf(a2.y, b2.y, s); s = fmaf(a2.z, b2.z, s); s = fmaf(a2.w, b2.w, s);
  s = fmaf(a3.x, b3.x, s); s = fmaf(a3.y, b3.y, s); s = fmaf(a3.z, b3.z, s); s = fmaf(a3.w, b3.w, s);
  return s;
}

// -------- kernel 1: assignment + cw_embed + one_hot (zeros + scatter) + idx --------
// grid = 512 blocks: blockIdx = d*2 + b-half.  block = 256 thr = 4 waves.
// wave w scans k-quarter [256w, 256w+256) for 128 b's (2 per lane).
// LDS 72 KB -> 2 blocks/CU = 8 waves/CU.
__global__ __launch_bounds__(256, 2) void vq_assign(
    const float* __restrict__ cw_q,      // (B, D*E)
    const float* __restrict__ codebook,  // (D, K, E)
    float* __restrict__ out,
    int* __restrict__ idx_ws)            // (D, B) ints
{
  __shared__ float4 cb4s[KK * EE / 4];   // 64 KB: codebook row d
  __shared__ float  c2s[KK];             // 4 KB
  __shared__ float  pbest[4 * 128];      // 2 KB
  __shared__ int    pidxs[4 * 128];      // 2 KB

  const int t  = threadIdx.x;
  const int d  = blockIdx.x >> 1;
  const int hf = blockIdx.x & 1;
  const int w  = t >> 6;
  const int l  = t & 63;

  // --- issue x-fragment loads early (independent of staging) ---
  const int b0 = hf * 128 + l;
  const int b1 = b0 + 64;
  const float4* xr0 = (const float4*)cw_q + (size_t)b0 * (DD * EE / 4) + d * 4;
  const float4* xr1 = (const float4*)cw_q + (size_t)b1 * (DD * EE / 4) + d * 4;
  float4 xa0 = xr0[0], xb0 = xr0[1], xc0 = xr0[2], xd0 = xr0[3];
  float4 xa1 = xr1[0], xb1 = xr1[1], xc1 = xr1[2], xd1 = xr1[3];

  // --- stage codebook row d -> LDS; c2 via 4-lane butterfly (no atomics) ---
  const float4* src4 = (const float4*)codebook + (size_t)d * (KK * EE / 4);
  #pragma unroll
  for (int i = 0; i < 16; ++i) {
    int i4 = i * 256 + t;
    float4 v = src4[i4];
    cb4s[i4] = v;
    float sq = v.x * v.x;
    sq = fmaf(v.y, v.y, sq);
    sq = fmaf(v.z, v.z, sq);
    sq = fmaf(v.w, v.w, sq);
    sq += __shfl_xor(sq, 1);
    sq += __shfl_xor(sq, 2);
    if ((t & 3) == 0) c2s[i4 >> 2] = sq;
  }
  __syncthreads();

  const float x2_0 = dot16(xa0, xb0, xc0, xd0, xa0, xb0, xc0, xd0);
  const float x2_1 = dot16(xa1, xb1, xc1, xd1, xa1, xb1, xc1, xd1);

  float best0 = FLT_MAX, best1 = FLT_MAX;
  int   bi0 = 0, bi1 = 0;
  const int kbase = w << 8;

  // zero-fill base for this wave (float2 units); row stride = D*K floats
  float2* zbase = (float2*)(out + OH_OFF + (size_t)(hf * 128) * (DD * KK)
                            + (size_t)d * KK + kbase) + l;

  #pragma unroll 2
  for (int s = 0; s < 256; ++s) {
    const int k = kbase + s;
    const float4* p = cb4s + (k << 2);          // wave-uniform -> broadcast
    float4 c0 = p[0], c1 = p[1], c2v = p[2], c3 = p[3];

    float dot0 = dot16(c0, c1, c2v, c3, xa0, xb0, xc0, xd0);
    float dot1 = dot16(c0, c1, c2v, c3, xa1, xb1, xc1, xd1);
    const float c2k = c2s[k];
    float d0 = fmaf(-2.f, dot0, x2_0 + c2k);
    float d1 = fmaf(-2.f, dot1, x2_1 + c2k);
    if (d0 < best0) { best0 = d0; bi0 = k; }    // strict < : first-occurrence ties
    if (d1 < best1) { best1 = d1; bi1 = k; }

    // interleaved one_hot zero-fill: iter s -> local row r=s>>1, half hh=s&1
    const int r  = s >> 1;
    const int hh = s & 1;
    zbase[(size_t)r * (DD * KK / 2) + hh * 64] = make_float2(0.f, 0.f);
  }

  pbest[w * 128 + l]      = best0;  pidxs[w * 128 + l]      = bi0;
  pbest[w * 128 + l + 64] = best1;  pidxs[w * 128 + l + 64] = bi1;
  __syncthreads();   // drains zero-stores (vmcnt) + LDS partials

  // --- merge k-quarters in ascending-k order (strict <), epilogue ---
  if (t < 128) {
    float bb = pbest[t];
    int   bi = pidxs[t];
    #pragma unroll
    for (int w2 = 1; w2 < 4; ++w2) {
      float e = pbest[w2 * 128 + t];
      int   ii = pidxs[w2 * 128 + t];
      if (e < bb) { bb = e; bi = ii; }
    }
    const int b = hf * 128 + t;

    float4* ce = (float4*)out + (size_t)b * (DD * EE / 4) + d * 4;
    const float4* cw = cb4s + (bi << 2);
    ce[0] = cw[0]; ce[1] = cw[1]; ce[2] = cw[2]; ce[3] = cw[3];

    out[OH_OFF + (size_t)b * (DD * KK) + (size_t)d * KK + bi] = 1.0f;

    idx_ws[d * BB + b] = bi;
  }
}

// -------- kernel 2: counts/update from idx, new_ema + new_codebook --------
// grid = 256 (one per d), 256 thr.
__global__ __launch_bounds__(256) void vq_update(
    const float* __restrict__ cw_q,
    const float* __restrict__ codebook,
    const float* __restrict__ ema,
    const int* __restrict__ idx_ws,
    float* __restrict__ out)
{
  __shared__ float upds[KK * EE];   // 64 KB
  __shared__ float cnts[KK];        // 4 KB
  __shared__ float esh[KK];         // 4 KB
  __shared__ int   ish[BB];         // 1 KB

  const int t = threadIdx.x;
  const int d = blockIdx.x;
  float4* upd4 = (float4*)upds;
  const float4 z4 = make_float4(0.f, 0.f, 0.f, 0.f);

  #pragma unroll
  for (int i = 0; i < 16; ++i) upd4[i * 256 + t] = z4;
  #pragma unroll
  for (int j = 0; j < 4; ++j) cnts[t + 256 * j] = 0.f;
  __syncthreads();

  {
    int kidx = idx_ws[d * BB + t];
    ish[t] = kidx;
    atomicAdd(&cnts[kidx], 1.0f);
  }
  __syncthreads();

  // e-split scatter: e = t&15 spreads atomic addresses across banks
  {
    const int e = t & 15;
    const int g = t >> 4;            // 16 groups of 16 b's
    #pragma unroll
    for (int i = 0; i < 16; ++i) {
      int b = g * 16 + i;
      int k = ish[b];
      float xv = cw_q[(size_t)b * (DD * EE) + (size_t)d * EE + e];
      atomicAdd(&upds[k * EE + e], xv);
    }
  }
  __syncthreads();

  // new_ema + stage ema
  const float* emad = ema + (size_t)d * KK;
  float* out_ema    = out + EMA_OFF + (size_t)d * KK;
  #pragma unroll
  for (int j = 0; j < 4; ++j) {
    int k = t + 256 * j;
    float ev = emad[k];
    esh[k] = ev;
    out_ema[k] = DECAY * ev + GAIN * cnts[k];
  }
  __syncthreads();

  // new_codebook (streaming, same arithmetic shape as round-1's passing version)
  const float4* cb4 = (const float4*)codebook + (size_t)d * (KK * EE / 4);
  float4* ocb4      = (float4*)(out + CB_OFF) + (size_t)d * (KK * EE / 4);
  #pragma unroll
  for (int i = 0; i < 16; ++i) {
    int i4 = i * 256 + t;
    int k  = i4 >> 2;
    float4 c = cb4[i4];
    float4 u = upd4[i4];
    float inv = GAIN / (esh[k] + EPS);
    float4 r;
    r.x = DECAY * c.x + u.x * inv;
    r.y = DECAY * c.y + u.y * inv;
    r.z = DECAY * c.z + u.z * inv;
    r.w = DECAY * c.w + u.w * inv;
    ocb4[i4] = r;
  }
}

extern "C" void kernel_launch(void* const* d_in, const int* in_sizes, int n_in,
                              void* d_out, int out_size, void* d_ws, size_t ws_size,
                              hipStream_t stream) {
  const float* cw_q     = (const float*)d_in[0];
  const float* codebook = (const float*)d_in[1];
  const float* ema      = (const float*)d_in[2];
  float* out  = (float*)d_out;
  int* idx_ws = (int*)d_ws;   // 256 KB
  (void)in_sizes; (void)n_in; (void)out_size; (void)ws_size;

  vq_assign<<<dim3(512), dim3(256), 0, stream>>>(cw_q, codebook, out, idx_ws);
  vq_update<<<dim3(256), dim3(256), 0, stream>>>(cw_q, codebook, ema, idx_ws, out);
}

// Round 3
// 318.479 us; speedup vs baseline: 1.0284x; 1.0284x over previous
//
#include <hip/hip_runtime.h>
#include <float.h>

#define BB 256
#define DD 256
#define KK 1024
#define EE 16
#define DECAY 0.999f
#define GAIN  0.001f
#define EPS   1e-6f

// output offsets in floats (tuple order: cw_embed, one_hot, new_codebook, new_ema)
#define OH_OFF   ((size_t)BB * DD * EE)                    // 1048576
#define CB_OFF   (OH_OFF + (size_t)BB * DD * KK)           // 68157440
#define EMA_OFF  (CB_OFF + (size_t)DD * KK * EE)           // 72351744

__device__ __forceinline__ float dot16(const float4& a0, const float4& a1,
                                       const float4& a2, const float4& a3,
                                       const float4& b0, const float4& b1,
                                       const float4& b2, const float4& b3) {
  float s = a0.x * b0.x;
  s = fmaf(a0.y, b0.y, s); s = fmaf(a0.z, b0.z, s); s = fmaf(a0.w, b0.w, s);
  s = fmaf(a1.x, b1.x, s); s = fmaf(a1.y, b1.y, s); s = fmaf(a1.z, b1.z, s); s = fmaf(a1.w, b1.w, s);
  s = fmaf(a2.x, b2.x, s); s = fmaf(a2.y, b2.y, s); s = fmaf(a2.z, b2.z, s); s = fmaf(a2.w, b2.w, s);
  s = fmaf(a3.x, b3.x, s); s = fmaf(a3.y, b3.y, s); s = fmaf(a3.z, b3.z, s); s = fmaf(a3.w, b3.w, s);
  return s;
}

// One block per d. 512 threads = 8 waves. Wave w scans k in [128w, 128w+128);
// each lane holds x for 4 b's (b = lane + 64j) -> 1 ds_read_b128 per dot.
// one_hot zero-fill interleaved as full float4 (1 KB/wave-instr) stores.
// LDS ~153 KB -> 1 block/CU, 8 waves/CU.
__global__ __launch_bounds__(512, 2) void vqvae_fused(
    const float* __restrict__ cw_q,      // (B, D*E)
    const float* __restrict__ codebook,  // (D, K, E)
    const float* __restrict__ ema,       // (D, K)
    float* __restrict__ out)
{
  __shared__ float4 cb4s[KK * EE / 4];   // 64 KB codebook row d
  __shared__ float4 upd4s[KK * EE / 4];  // 64 KB update accumulator
  __shared__ float  c2s[KK];             // 4 KB |c|^2, reused as esh
  __shared__ float  cnts[KK];            // 4 KB
  __shared__ float  pbest[8 * 256];      // 8 KB
  __shared__ int    pidxs[8 * 256];      // 8 KB
  __shared__ int    ish[BB];             // 1 KB

  const int t = threadIdx.x;
  const int d = blockIdx.x;
  const int w = t >> 6;
  const int l = t & 63;
  const float4 z4 = make_float4(0.f, 0.f, 0.f, 0.f);

  // ---- P0a: zero LDS accumulators ----
  #pragma unroll
  for (int j = 0; j < 2; ++j) cnts[t + 512 * j] = 0.f;
  #pragma unroll
  for (int i = 0; i < 8; ++i) upd4s[i * 512 + t] = z4;

  // ---- P0b: stage codebook row d -> LDS; c2 via 4-lane butterfly ----
  const float4* src4 = (const float4*)codebook + (size_t)d * (KK * EE / 4);
  #pragma unroll
  for (int i = 0; i < 8; ++i) {
    int i4 = i * 512 + t;
    float4 v = src4[i4];
    cb4s[i4] = v;
    float sq = v.x * v.x;
    sq = fmaf(v.y, v.y, sq);
    sq = fmaf(v.z, v.z, sq);
    sq = fmaf(v.w, v.w, sq);
    sq += __shfl_xor(sq, 1);
    sq += __shfl_xor(sq, 2);
    if ((t & 3) == 0) c2s[i4 >> 2] = sq;
  }

  // ---- x fragments for 4 b's per lane (b = l + 64j) ----
  float4 xv[4][4];
  float  x2[4];
  #pragma unroll
  for (int j = 0; j < 4; ++j) {
    const int b = l + 64 * j;
    const float4* xr = (const float4*)cw_q + (size_t)b * (DD * EE / 4) + d * 4;
    xv[j][0] = xr[0]; xv[j][1] = xr[1]; xv[j][2] = xr[2]; xv[j][3] = xr[3];
  }
  __syncthreads();

  #pragma unroll
  for (int j = 0; j < 4; ++j)
    x2[j] = dot16(xv[j][0], xv[j][1], xv[j][2], xv[j][3],
                  xv[j][0], xv[j][1], xv[j][2], xv[j][3]);

  float best[4] = {FLT_MAX, FLT_MAX, FLT_MAX, FLT_MAX};
  int   bi[4]   = {0, 0, 0, 0};
  const int kbase = w << 7;

  float* ohp = out + OH_OFF;
  // wave w zero-fills one_hot rows [32w, 32w+32) for column block d (all 1024 k)
  float4* zb = (float4*)(ohp + (size_t)(w << 5) * (DD * KK) + (size_t)d * KK) + l;

  #pragma unroll 2
  for (int s = 0; s < 128; ++s) {
    const int k = kbase + s;
    const float4* p = cb4s + (k << 2);     // wave-uniform -> LDS broadcast
    float4 c0 = p[0], c1 = p[1], c2v = p[2], c3 = p[3];
    const float c2k = c2s[k];

    #pragma unroll
    for (int j = 0; j < 4; ++j) {
      float dj = dot16(c0, c1, c2v, c3, xv[j][0], xv[j][1], xv[j][2], xv[j][3]);
      float dist = fmaf(-2.f, dj, x2[j] + c2k);
      if (dist < best[j]) { best[j] = dist; bi[j] = k; }   // strict <: lowest k wins
    }

    // interleaved zero-fill: iter s -> local row s>>2, k-quarter s&3 (1 KB/wave)
    zb[(size_t)(s >> 2) * (DD * KK / 4) + (s & 3) * 64] = z4;
  }

  #pragma unroll
  for (int j = 0; j < 4; ++j) {
    pbest[w * 256 + l + 64 * j] = best[j];
    pidxs[w * 256 + l + 64 * j] = bi[j];
  }
  __syncthreads();   // drains zero-stores (vmcnt) + LDS partials

  // ---- P2: merge 8 k-ranges (ascending k, strict <), epilogue per b ----
  if (t < 256) {
    const int b = t;
    float bb = pbest[b];
    int   bidx = pidxs[b];
    #pragma unroll
    for (int w2 = 1; w2 < 8; ++w2) {
      float e = pbest[w2 * 256 + b];
      int   ii = pidxs[w2 * 256 + b];
      if (e < bb) { bb = e; bidx = ii; }
    }

    float4* ce = (float4*)out + (size_t)b * (DD * EE / 4) + d * 4;
    const float4* cwp = cb4s + (bidx << 2);
    ce[0] = cwp[0]; ce[1] = cwp[1]; ce[2] = cwp[2]; ce[3] = cwp[3];

    ohp[(size_t)b * (DD * KK) + (size_t)d * KK + bidx] = 1.0f;

    ish[b] = bidx;
    atomicAdd(&cnts[bidx], 1.0f);
  }
  __syncthreads();

  // ---- P3: update scatter, e-split so atomic addresses spread across banks ----
  {
    float* upd = (float*)upd4s;
    const int e = t & 15;
    const int g = t >> 4;                  // 32 groups handle 8 b's each
    #pragma unroll
    for (int i = 0; i < 8; ++i) {
      int b = g * 8 + i;
      int k = ish[b];
      float xvv = cw_q[(size_t)b * (DD * EE) + (size_t)d * EE + e];  // L1-hot
      atomicAdd(&upd[k * EE + e], xvv);
    }
  }
  __syncthreads();

  // ---- P4: new_ema + stage ema (reuse c2s) ----
  {
    const float* emad = ema + (size_t)d * KK;
    float* oe = out + EMA_OFF + (size_t)d * KK;
    #pragma unroll
    for (int j = 0; j < 2; ++j) {
      int k = t + 512 * j;
      float ev = emad[k];
      c2s[k] = ev;
      oe[k] = DECAY * ev + GAIN * cnts[k];
    }
  }
  __syncthreads();

  // ---- P5: new_codebook ----
  {
    float4* ocb = (float4*)(out + CB_OFF) + (size_t)d * (KK * EE / 4);
    #pragma unroll
    for (int i = 0; i < 8; ++i) {
      int i4 = i * 512 + t;
      int k  = i4 >> 2;
      float4 c = cb4s[i4];
      float4 u = upd4s[i4];
      float inv = GAIN / (c2s[k] + EPS);
      float4 r;
      r.x = DECAY * c.x + u.x * inv;
      r.y = DECAY * c.y + u.y * inv;
      r.z = DECAY * c.z + u.z * inv;
      r.w = DECAY * c.w + u.w * inv;
      ocb[i4] = r;
    }
  }
}

extern "C" void kernel_launch(void* const* d_in, const int* in_sizes, int n_in,
                              void* d_out, int out_size, void* d_ws, size_t ws_size,
                              hipStream_t stream) {
  const float* cw_q     = (const float*)d_in[0];
  const float* codebook = (const float*)d_in[1];
  const float* ema      = (const float*)d_in[2];
  float* out = (float*)d_out;
  (void)in_sizes; (void)n_in; (void)out_size; (void)d_ws; (void)ws_size;

  vqvae_fused<<<dim3(DD), dim3(512), 0, stream>>>(cw_q, codebook, ema, out);
}